// Round 5
// baseline (526.085 us; speedup 1.0000x reference)
//
#include <hip/hip_runtime.h>
#include <cstdint>

typedef _Float16 f16x8 __attribute__((ext_vector_type(8)));
typedef float f32x4 __attribute__((ext_vector_type(4)));

typedef __attribute__((address_space(1))) void gvoid;
typedef __attribute__((address_space(3))) void lvoid;

__device__ __forceinline__ void gload16(const void* g, void* l) {
    __builtin_amdgcn_global_load_lds((gvoid*)g, (lvoid*)l, 16, 0, 0);
}

__device__ __forceinline__ void bar() {
    asm volatile("" ::: "memory");
    __builtin_amdgcn_s_barrier();
    asm volatile("" ::: "memory");
}
#define WAITV(N) asm volatile("s_waitcnt vmcnt(" #N ")" ::: "memory")

// ---------------------------------------------------------------------------
__global__ __launch_bounds__(256) void downsample_kernel(const float* __restrict__ f,
                                                         const float* __restrict__ b,
                                                         float* __restrict__ fds,
                                                         float* __restrict__ bds) {
    int idx = blockIdx.x * 256 + threadIdx.x;
    const float* src = blockIdx.y ? b : f;
    float* dst = blockIdx.y ? bds : fds;
    int bb = idx >> 19;
    int r = idx & 524287;
    int c = r >> 12, a = (r >> 6) & 63, v = r & 63;
    dst[idx] = src[(size_t)bb * 2097152 + (size_t)c * 16384 + (2 * a) * 128 + 2 * v];
}

// ---------------------------------------------------------------------------
__global__ __launch_bounds__(256) void build_mm_kernel(const float* __restrict__ mask,
                                                       float* __restrict__ mm) {
    int l = blockIdx.x * 256 + threadIdx.x;
    if (l >= 4096) return;
    int i = l >> 6, j = l & 63;
    float s = 0.f;
    #pragma unroll
    for (int dy = 0; dy < 3; ++dy)
        #pragma unroll
        for (int dx = 0; dx < 3; ++dx) {
            int a = i + dy - 1, b = j + dx - 1;
            if ((unsigned)a < 64u && (unsigned)b < 64u)
                s += mask[(2 * a) * 128 + 2 * b];
        }
    mm[l] = (s == 0.0f) ? 1.0f : 0.0f;
}

// ---------------------------------------------------------------------------
__global__ __launch_bounds__(256) void build_fpatch_kernel(const float* __restrict__ fds,
                                                           _Float16* __restrict__ Fp) {
    int bb = blockIdx.x >> 12;
    int p = blockIdx.x & 4095;
    const float* fb = fds + (size_t)bb * 524288;
    _Float16* Fpb = Fp + (size_t)bb * 4718592;
    int u = p >> 6, v = p & 63;
    for (int k = threadIdx.x; k < 1152; k += 256) {
        int c = k / 9;
        int s = k - 9 * c;
        int dy = s / 3, dx = s - 3 * dy;
        int a = u + dy - 1, bcol = v + dx - 1;
        float val = 0.f;
        if ((unsigned)a < 64u && (unsigned)bcol < 64u)
            val = fb[c * 4096 + a * 64 + bcol];
        Fpb[(size_t)p * 1152 + k] = (_Float16)val;
    }
}

// ---------------------------------------------------------------------------
__global__ __launch_bounds__(256) void build_wn_kernel(const float* __restrict__ bds,
                                                       _Float16* __restrict__ Wn) {
    __shared__ float wsh[1152];
    __shared__ float red[4];
    int bb = blockIdx.x >> 12;
    int l = blockIdx.x & 4095;
    const float* bp = bds + (size_t)bb * 524288;
    _Float16* Wnb = Wn + (size_t)bb * 4718592;
    int i = l >> 6, j = l & 63;
    float sq = 0.f;
    for (int k = threadIdx.x; k < 1152; k += 256) {
        int c = k / 9;
        int s = k - 9 * c;
        int dy = s / 3, dx = s - 3 * dy;
        int a = i + dy - 1, bcol = j + dx - 1;
        float val = 0.f;
        if ((unsigned)a < 64u && (unsigned)bcol < 64u)
            val = bp[c * 4096 + a * 64 + bcol];
        wsh[k] = val;
        sq += val * val;
    }
    #pragma unroll
    for (int off = 32; off > 0; off >>= 1) sq += __shfl_xor(sq, off);
    if ((threadIdx.x & 63) == 0) red[threadIdx.x >> 6] = sq;
    __syncthreads();
    float total = red[0] + red[1] + red[2] + red[3] + 0.1152f;
    float rinv = 1.0f / sqrtf(total);
    for (int k = threadIdx.x; k < 1152; k += 256)
        Wnb[(size_t)l * 1152 + k] = (_Float16)(wsh[k] * rinv);
}

// ---------------------------------------------------------------------------
__global__ __launch_bounds__(256) void build_vt_kernel(const float* __restrict__ b,
                                                       _Float16* __restrict__ Vt) {
    int bb = blockIdx.x >> 11;
    int n = blockIdx.x & 2047;
    const float* bp = b + (size_t)bb * 2097152;
    _Float16* Vtb = Vt + (size_t)bb * 8388608;
    int c = n >> 4, r = n & 15, rh = r >> 2, rw = r & 3;
    const float* bc = bp + (size_t)c * 16384;
    for (int l = threadIdx.x; l < 4096; l += 256) {
        int lh = l >> 6, lw = l & 63;
        int row = 2 * lh + rh - 1, col = 2 * lw + rw - 1;
        float val = 0.f;
        if ((unsigned)row < 128u && (unsigned)col < 128u)
            val = bc[row * 128 + col];
        Vtb[(size_t)n * 4096 + l] = (_Float16)val;
    }
}

// ---------------------------------------------------------------------------
// 256x256/BK=64 8-phase core, B-operand DIRECT global->VGPR (no LDS for B).
// A stays LDS-staged (read by 4 waves each; swizzled source, linear DMA dest).
// B frags double-banked (bfr0/bfr1), issued 2 phases before use; completion
// enforced by counted vmcnt (async) instead of same-phase lgkmcnt(0).
// Phase p = (tile, kc, mh): MFMA burst = 4mi x 4ni at K-chunk kc (32 wide).
// Per-phase vmcnt events (odd phases): LDB(4) then STAGE(2), order pinned by
// sched_barrier(0); even phases: none. Wait calculus (derived, steady state):
//   p1: WAITV(6)  completes prev-p7 BF (bfr0) + all older staging
//   p3/p5/p7: WAITV(8) completes the BF issued 2 phases earlier + staging
// A-region schedule (unchanged from R1, verified): p1 stages buf1.kh1<-t0+1,
// p3 buf0.kh0<-t0+2, p5 buf0.kh1<-t0+2, p7 buf1.kh0<-t0+3; every region
// complete >=1 barrier before first read. Accumulation order per acc element
// (ascending 32-K chunks) unchanged -> numerics identical.
template <int KSTR, int NTILES>
__device__ __forceinline__ void gemm_core(const _Float16* __restrict__ A,
                                          const _Float16* __restrict__ Bt,
                                          _Float16* __restrict__ C,
                                          _Float16* __restrict__ AsB) {
    const int tid = threadIdx.x;
    const int lane = tid & 63;
    const int wave = tid >> 6;
    const int quad = lane >> 4;
    const int l16 = lane & 15;
    const int wm = wave >> 2;
    const int wn = wave & 3;
    const int bm = blockIdx.y * 256;
    const int bn = blockIdx.x * 256;

    f32x4 acc[8][4] = {};

    const int s0 = tid, s1 = 512 + tid;
    const int sr0 = s0 >> 2, sr1 = s1 >> 2;
    const int r0 = sr0 ^ ((sr0 >> 2) & 1);
    const int r1 = sr1 ^ ((sr1 >> 2) & 1);
    const int q0 = (s0 & 3) ^ (r0 & 3);
    const int q1 = (s1 & 3) ^ (r1 & 3);
    const int offA0 = (bm + r0) * KSTR + q0 * 8;
    const int offA1 = (bm + r1) * KSTR + q1 * 8;

#define STAGE(buf, kt, kh) do {                                                            \
        gload16(A + offA0 + (kt) * 64 + (kh) * 32, AsB + ((buf) * 2 + (kh)) * 8192 + tid * 8); \
        gload16(A + offA1 + (kt) * 64 + (kh) * 32, AsB + ((buf) * 2 + (kh)) * 8192 + 4096 + tid * 8); \
    } while (0)

    const int c2 = (l16 >> 2) & 1;
    const int rdoff = ((l16 ^ c2) * 32) + ((quad ^ (l16 & 3)) * 8);

    f16x8 afr[4], bfr0[4], bfr1[4];
    const _Float16* bB = Bt + (size_t)(bn + wn * 64 + l16) * KSTR + quad * 8;

    // 4 x global_load_dwordx4 (16 rows x 64B coalesced segments, L1-resident
    // across the 2 sharing waves). Issued 2 phases before consumption.
#define LDB(dst, kt, kc) do {                                                              \
        _Pragma("unroll")                                                                  \
        for (int ni = 0; ni < 4; ++ni)                                                     \
            dst[ni] = *(const f16x8*)(bB + (size_t)ni * 16 * KSTR + (kt) * 64 + (kc) * 32); \
        __builtin_amdgcn_sched_barrier(0);                                                 \
    } while (0)

    auto LDA = [&](int buf, int kh, int mh) {
        #pragma unroll
        for (int mi = 0; mi < 4; ++mi)
            afr[mi] = *(const f16x8*)&AsB[((buf) * 2 + (kh)) * 8192 +
                                          (wm * 128 + ((mh) * 4 + mi) * 16) * 32 + rdoff];
    };
#define MM(bf, mh) do {                                                                    \
        __builtin_amdgcn_s_setprio(1);                                                     \
        _Pragma("unroll")                                                                  \
        for (int mi = 0; mi < 4; ++mi)                                                     \
            _Pragma("unroll")                                                              \
            for (int ni = 0; ni < 4; ++ni)                                                 \
                acc[(mh) * 4 + mi][ni] = __builtin_amdgcn_mfma_f32_16x16x32_f16(           \
                    afr[mi], bf[ni], acc[(mh) * 4 + mi][ni], 0, 0, 0);                     \
        __builtin_amdgcn_s_setprio(0);                                                     \
    } while (0)

    // prologue: A tile0 (both kh) + tile1.kh0; B frags for p1
    LDB(bfr0, 0, 0);
    STAGE(0, 0, 0);
    STAGE(0, 0, 1);
    STAGE(1, 1, 0);
    WAITV(4);
    bar();

    #pragma unroll 1
    for (int i = 0; i < NTILES / 2 - 1; ++i) {
        const int t0 = 2 * i;
        // p1 (t0, kc0, mh0)
        LDB(bfr1, t0, 1); STAGE(1, t0 + 1, 1); LDA(0, 0, 0); WAITV(6);
        bar(); MM(bfr0, 0); bar();
        // p2 (t0, kc0, mh1)
        LDA(0, 0, 1);
        bar(); MM(bfr0, 1); bar();
        // p3 (t0, kc1, mh0)
        LDB(bfr0, t0 + 1, 0); STAGE(0, t0 + 2, 0); LDA(0, 1, 0); WAITV(8);
        bar(); MM(bfr1, 0); bar();
        // p4 (t0, kc1, mh1)
        LDA(0, 1, 1);
        bar(); MM(bfr1, 1); bar();
        // p5 (t0+1, kc0, mh0)
        LDB(bfr1, t0 + 1, 1); STAGE(0, t0 + 2, 1); LDA(1, 0, 0); WAITV(8);
        bar(); MM(bfr0, 0); bar();
        // p6 (t0+1, kc0, mh1)
        LDA(1, 0, 1);
        bar(); MM(bfr0, 1); bar();
        // p7 (t0+1, kc1, mh0)
        LDB(bfr0, t0 + 2, 0); STAGE(1, t0 + 3, 0); LDA(1, 1, 0); WAITV(8);
        bar(); MM(bfr1, 0); bar();
        // p8 (t0+1, kc1, mh1)
        LDA(1, 1, 1);
        bar(); MM(bfr1, 1); bar();
    }

    // epilogue: tiles NTILES-2 (buf0), NTILES-1 (buf1); stage buf1.kh1 only
    LDB(bfr1, NTILES - 2, 1); STAGE(1, NTILES - 1, 1); LDA(0, 0, 0); WAITV(8);
    bar(); MM(bfr0, 0); bar();
    LDA(0, 0, 1);
    bar(); MM(bfr0, 1); bar();
    LDB(bfr0, NTILES - 1, 0); LDA(0, 1, 0); WAITV(6);
    bar(); MM(bfr1, 0); bar();
    LDA(0, 1, 1);
    bar(); MM(bfr1, 1); bar();
    LDB(bfr1, NTILES - 1, 1); LDA(1, 0, 0); WAITV(4);
    bar(); MM(bfr0, 0); bar();
    LDA(1, 0, 1);
    bar(); MM(bfr0, 1); bar();
    LDA(1, 1, 0); WAITV(0);
    bar(); MM(bfr1, 0); bar();
    LDA(1, 1, 1);
    bar(); MM(bfr1, 1);

#undef STAGE
#undef LDB
#undef MM

    #pragma unroll
    for (int mi = 0; mi < 8; ++mi)
        #pragma unroll
        for (int ni = 0; ni < 4; ++ni)
            #pragma unroll
            for (int r = 0; r < 4; ++r) {
                int row = bm + wm * 128 + mi * 16 + quad * 4 + r;
                int col = bn + wn * 64 + ni * 16 + l16;
                C[(size_t)row * 4096 + col] = (_Float16)acc[mi][ni][r];
            }
}

// ---------------------------------------------------------------------------
__global__ __launch_bounds__(512, 2) void gemm1_kernel(const _Float16* __restrict__ Fp,
                                                       const _Float16* __restrict__ Wn,
                                                       _Float16* __restrict__ S0) {
    __shared__ __align__(16) _Float16 As[2][2][8192];
    const int z = blockIdx.z;
    gemm_core<1152, 18>(Fp + (size_t)z * 4718592, Wn + (size_t)z * 4718592,
                        S0 + (size_t)z * 16777216, &As[0][0][0]);
}

// ---------------------------------------------------------------------------
__global__ __launch_bounds__(512, 2) void gemm2_kernel(const _Float16* __restrict__ Vt,
                                                       const _Float16* __restrict__ att0,
                                                       const _Float16* __restrict__ att1,
                                                       _Float16* __restrict__ OTh) {
    __shared__ __align__(16) _Float16 As[2][2][8192];
    const int z = blockIdx.z;
    gemm_core<4096, 64>(Vt + (size_t)z * 8388608, z ? att1 : att0,
                        OTh + (size_t)z * 8388608, &As[0][0][0]);
}

// ---------------------------------------------------------------------------
// Fused double 3-tap "fuse" + mask + softmax (R8 body, XCD swizzle, both
// batches in one dispatch).
__global__ __launch_bounds__(256) void fuse_softmax_kernel(const _Float16* __restrict__ S0,
                                                           const float* __restrict__ mm,
                                                           _Float16* __restrict__ att0,
                                                           _Float16* __restrict__ att1) {
    __shared__ float red[4];
    const int tid = threadIdx.x;
    const int lane = tid & 63;
    const int wave = tid >> 6;
    int g = blockIdx.x;
    int p_global = ((g & 7) << 10) | (g >> 3);
    const int bb = p_global >> 12;
    const int p = p_global & 4095;
    const _Float16* S = S0 + (size_t)bb * 16777216;
    _Float16* att = bb ? att1 : att0;
    const int pbase = ((p & 63) << 6) | (p >> 6);  // T(p)

    float acc[16];
    #pragma unroll
    for (int k = 0; k < 16; ++k) acc[k] = 0.f;

    #pragma unroll
    for (int t2 = -1; t2 <= 1; ++t2) {
        int b2 = pbase + t2;
        if ((unsigned)b2 >= 4096u) continue;
        int pp = ((b2 & 63) << 6) | (b2 >> 6);
        #pragma unroll
        for (int t1 = -1; t1 <= 1; ++t1) {
            int rr = pp + t1;
            if ((unsigned)rr >= 4096u) continue;
            const _Float16* row = S + (size_t)rr * 4096;
            #pragma unroll
            for (int k = 0; k < 16; ++k) {
                int l = k * 256 + tid;
                int i = (k * 256 + wave * 64) >> 6;
                int it2 = i + t2;
                if (it2 >= 0 && it2 < 64) {
                    int c = l + t2 * 64 + t1;
                    if ((unsigned)c < 4096u)
                        acc[k] += (float)row[c];
                } else if (it2 == 64) {
                    if (lane <= 62) {
                        int c = lane + 1 + t1;
                        if ((unsigned)c < 4096u) acc[k] += (float)row[c];
                    }
                } else {
                    if (lane >= 1) {
                        int c = 4031 + lane + t1;
                        if ((unsigned)c < 4096u) acc[k] += (float)row[c];
                    }
                }
            }
        }
    }

    float mv[16];
    float lmax = -1e30f;
    #pragma unroll
    for (int k = 0; k < 16; ++k) {
        int l = k * 256 + tid;
        mv[k] = mm[l];
        float lg = acc[k] * mv[k] * 10.0f;
        acc[k] = lg;
        lmax = fmaxf(lmax, lg);
    }
    #pragma unroll
    for (int off = 32; off > 0; off >>= 1) lmax = fmaxf(lmax, __shfl_xor(lmax, off));
    if (lane == 0) red[wave] = lmax;
    __syncthreads();
    lmax = fmaxf(fmaxf(red[0], red[1]), fmaxf(red[2], red[3]));
    __syncthreads();

    float lsum = 0.f;
    #pragma unroll
    for (int k = 0; k < 16; ++k) {
        float e = __expf(acc[k] - lmax);
        acc[k] = e;
        lsum += e;
    }
    #pragma unroll
    for (int off = 32; off > 0; off >>= 1) lsum += __shfl_xor(lsum, off);
    if (lane == 0) red[wave] = lsum;
    __syncthreads();
    float inv = 1.0f / (red[0] + red[1] + red[2] + red[3]);
    #pragma unroll
    for (int k = 0; k < 16; ++k) {
        int l = k * 256 + tid;
        att[(size_t)p * 4096 + l] = (_Float16)(acc[k] * inv * mv[k]);
    }
}

// ---------------------------------------------------------------------------
__global__ __launch_bounds__(256) void assemble_kernel(const _Float16* __restrict__ OTh,
                                                       float* __restrict__ out) {
    int idx = blockIdx.x * 256 + threadIdx.x;
    int bb = idx >> 21;
    int w = idx & 2097151;
    const _Float16* OTb = OTh + (size_t)bb * 8388608;
    int x = w & 127, y = (w >> 7) & 127, c = w >> 14;
    int r0 = (y + 1) & 1, s0 = (x + 1) & 1;
    float acc = 0.f;
    #pragma unroll
    for (int a = 0; a < 2; ++a) {
        int rh = r0 + 2 * a;
        int ph = (y + 1 - rh) >> 1;
        if ((unsigned)ph < 64u) {
            #pragma unroll
            for (int bq = 0; bq < 2; ++bq) {
                int rw = s0 + 2 * bq;
                int pw = (x + 1 - rw) >> 1;
                if ((unsigned)pw < 64u)
                    acc += (float)OTb[(size_t)(c * 16 + rh * 4 + rw) * 4096 + ph * 64 + pw];
            }
        }
    }
    out[idx] = 0.25f * acc;
}

// ---------------------------------------------------------------------------
extern "C" void kernel_launch(void* const* d_in, const int* in_sizes, int n_in,
                              void* d_out, int out_size, void* d_ws, size_t ws_size,
                              hipStream_t stream) {
    const float* f = (const float*)d_in[0];
    const float* b = (const float*)d_in[1];
    const float* mask = (const float*)d_in[2];
    float* out = (float*)d_out;
    char* ws = (char*)d_ws;

    // workspace — total 138,428,416 bytes (proven size)
    float* mm = (float*)ws;
    _Float16* Fp = (_Float16*)(ws + 16384);
    _Float16* Wn = (_Float16*)(ws + 16384 + 18874368);
    _Float16* att0 = (_Float16*)(ws + 16384);                 // overlays Fp/Wn (dead)
    _Float16* S0 = (_Float16*)(ws + 37765120);
    _Float16* Vt = (_Float16*)(ws + 37765120);                // overlays S0 b0 (dead)
    _Float16* OTh = (_Float16*)(ws + 37765120 + 33554432);    // overlays S0 b1 (dead)
    float* fds = (float*)(ws + 104873984);
    float* bds = (float*)(ws + 104873984 + 4194304);
    _Float16* att1 = (_Float16*)(ws + 104873984);             // overlays fds/bds (dead)

    downsample_kernel<<<dim3(4096, 2), 256, 0, stream>>>(f, b, fds, bds);
    build_mm_kernel<<<16, 256, 0, stream>>>(mask, mm);
    build_fpatch_kernel<<<8192, 256, 0, stream>>>(fds, Fp);
    build_wn_kernel<<<8192, 256, 0, stream>>>(bds, Wn);

    gemm1_kernel<<<dim3(16, 16, 2), 512, 0, stream>>>(Fp, Wn, S0);
    fuse_softmax_kernel<<<8192, 256, 0, stream>>>(S0, mm, att0, att1);

    build_vt_kernel<<<4096, 256, 0, stream>>>(b, Vt);
    gemm2_kernel<<<dim3(16, 8, 2), 512, 0, stream>>>(Vt, att0, att1, OTh);
    assemble_kernel<<<16384, 256, 0, stream>>>(OTh, out);
}

// Round 6
// 440.307 us; speedup vs baseline: 1.1948x; 1.1948x over previous
//
#include <hip/hip_runtime.h>
#include <cstdint>

typedef _Float16 f16x8 __attribute__((ext_vector_type(8)));
typedef float f32x4 __attribute__((ext_vector_type(4)));

typedef __attribute__((address_space(1))) void gvoid;
typedef __attribute__((address_space(3))) void lvoid;

__device__ __forceinline__ void gload16(const void* g, void* l) {
    __builtin_amdgcn_global_load_lds((gvoid*)g, (lvoid*)l, 16, 0, 0);
}

__device__ __forceinline__ void bar() {
    asm volatile("" ::: "memory");
    __builtin_amdgcn_s_barrier();
    asm volatile("" ::: "memory");
}
#define WAITV(N) asm volatile("s_waitcnt vmcnt(" #N ")" ::: "memory")
// Counted lgkm wait: drains all ds_reads EXCEPT the N most recently issued
// (DS completes in-order per wave). sched_barrier(0) pins the MFMA burst
// after the wait (rule #18: register-only MFMA can cross asm otherwise).
#define WAITL(N) do { asm volatile("s_waitcnt lgkmcnt(" #N ")" ::: "memory"); \
                      __builtin_amdgcn_sched_barrier(0); } while (0)

// ---------------------------------------------------------------------------
__global__ __launch_bounds__(256) void downsample_kernel(const float* __restrict__ f,
                                                         const float* __restrict__ b,
                                                         float* __restrict__ fds,
                                                         float* __restrict__ bds) {
    int idx = blockIdx.x * 256 + threadIdx.x;
    const float* src = blockIdx.y ? b : f;
    float* dst = blockIdx.y ? bds : fds;
    int bb = idx >> 19;
    int r = idx & 524287;
    int c = r >> 12, a = (r >> 6) & 63, v = r & 63;
    dst[idx] = src[(size_t)bb * 2097152 + (size_t)c * 16384 + (2 * a) * 128 + 2 * v];
}

// ---------------------------------------------------------------------------
__global__ __launch_bounds__(256) void build_mm_kernel(const float* __restrict__ mask,
                                                       float* __restrict__ mm) {
    int l = blockIdx.x * 256 + threadIdx.x;
    if (l >= 4096) return;
    int i = l >> 6, j = l & 63;
    float s = 0.f;
    #pragma unroll
    for (int dy = 0; dy < 3; ++dy)
        #pragma unroll
        for (int dx = 0; dx < 3; ++dx) {
            int a = i + dy - 1, b = j + dx - 1;
            if ((unsigned)a < 64u && (unsigned)b < 64u)
                s += mask[(2 * a) * 128 + 2 * b];
        }
    mm[l] = (s == 0.0f) ? 1.0f : 0.0f;
}

// ---------------------------------------------------------------------------
__global__ __launch_bounds__(256) void build_fpatch_kernel(const float* __restrict__ fds,
                                                           _Float16* __restrict__ Fp) {
    int bb = blockIdx.x >> 12;
    int p = blockIdx.x & 4095;
    const float* fb = fds + (size_t)bb * 524288;
    _Float16* Fpb = Fp + (size_t)bb * 4718592;
    int u = p >> 6, v = p & 63;
    for (int k = threadIdx.x; k < 1152; k += 256) {
        int c = k / 9;
        int s = k - 9 * c;
        int dy = s / 3, dx = s - 3 * dy;
        int a = u + dy - 1, bcol = v + dx - 1;
        float val = 0.f;
        if ((unsigned)a < 64u && (unsigned)bcol < 64u)
            val = fb[c * 4096 + a * 64 + bcol];
        Fpb[(size_t)p * 1152 + k] = (_Float16)val;
    }
}

// ---------------------------------------------------------------------------
__global__ __launch_bounds__(256) void build_wn_kernel(const float* __restrict__ bds,
                                                       _Float16* __restrict__ Wn) {
    __shared__ float wsh[1152];
    __shared__ float red[4];
    int bb = blockIdx.x >> 12;
    int l = blockIdx.x & 4095;
    const float* bp = bds + (size_t)bb * 524288;
    _Float16* Wnb = Wn + (size_t)bb * 4718592;
    int i = l >> 6, j = l & 63;
    float sq = 0.f;
    for (int k = threadIdx.x; k < 1152; k += 256) {
        int c = k / 9;
        int s = k - 9 * c;
        int dy = s / 3, dx = s - 3 * dy;
        int a = i + dy - 1, bcol = j + dx - 1;
        float val = 0.f;
        if ((unsigned)a < 64u && (unsigned)bcol < 64u)
            val = bp[c * 4096 + a * 64 + bcol];
        wsh[k] = val;
        sq += val * val;
    }
    #pragma unroll
    for (int off = 32; off > 0; off >>= 1) sq += __shfl_xor(sq, off);
    if ((threadIdx.x & 63) == 0) red[threadIdx.x >> 6] = sq;
    __syncthreads();
    float total = red[0] + red[1] + red[2] + red[3] + 0.1152f;
    float rinv = 1.0f / sqrtf(total);
    for (int k = threadIdx.x; k < 1152; k += 256)
        Wnb[(size_t)l * 1152 + k] = (_Float16)(wsh[k] * rinv);
}

// ---------------------------------------------------------------------------
__global__ __launch_bounds__(256) void build_vt_kernel(const float* __restrict__ b,
                                                       _Float16* __restrict__ Vt) {
    int bb = blockIdx.x >> 11;
    int n = blockIdx.x & 2047;
    const float* bp = b + (size_t)bb * 2097152;
    _Float16* Vtb = Vt + (size_t)bb * 8388608;
    int c = n >> 4, r = n & 15, rh = r >> 2, rw = r & 3;
    const float* bc = bp + (size_t)c * 16384;
    for (int l = threadIdx.x; l < 4096; l += 256) {
        int lh = l >> 6, lw = l & 63;
        int row = 2 * lh + rh - 1, col = 2 * lw + rw - 1;
        float val = 0.f;
        if ((unsigned)row < 128u && (unsigned)col < 128u)
            val = bc[row * 128 + col];
        Vtb[(size_t)n * 4096 + l] = (_Float16)val;
    }
}

// ---------------------------------------------------------------------------
// 256x256/BK=64 8-phase core, ROTATED READS + COUNTED lgkm (the m201
// mechanism R2-R4 missed). Phase p:
//   { STAGE; [WAITV(4) @p4,p8]; bar; reads(p+1)->bank; WAITL(R_{p+1});
//     setprio-MFMA(p from bank p-1); bar }
// MFMA(p) waits ONLY on reads(p) (issued in p-1); reads(p+1) stay in flight
// on the LDS pipe under the MFMA burst -> read-burst/MFMA-burst overlap.
// Static ping-pong banks: afrA/afrB flip per phase, bfrA/bfrB per 2 phases.
// Region guarantees (rotated reads land AFTER the WAITV+bar that completes
// their region; checked for all 4 regions + prologue/epilogue):
//   p4 WAITV(4) leaves {U3,U4}: completes prev-U7/U8 (buf1.kh0, read@p4) and
//   U1/U2 (buf1.kh1, read@p6). p8 WAITV(4) leaves {U7,U8}: completes U3/U4
//   (buf0.kh0, read@p8) and U5/U6 (buf0.kh1, read@p2-next).
// WAR: reads(p+1) drained by p+1's WAITL; region re-staged >=2 barriers later.
// Accumulation chunk order per acc element unchanged -> numerics identical.
template <int KSTR, int NTILES>
__device__ __forceinline__ void gemm_core(const _Float16* __restrict__ A,
                                          const _Float16* __restrict__ Bt,
                                          _Float16* __restrict__ C,
                                          _Float16* __restrict__ AsB,
                                          _Float16* __restrict__ BsB) {
    const int tid = threadIdx.x;
    const int lane = tid & 63;
    const int wave = tid >> 6;
    const int quad = lane >> 4;
    const int l16 = lane & 15;
    const int wm = wave >> 2;
    const int wn = wave & 3;
    const int bm = blockIdx.y * 256;
    const int bn = blockIdx.x * 256;

    f32x4 acc[8][4] = {};
    f16x8 afrA[4], afrB[4], bfrA[4], bfrB[4];

    const int s0 = tid, s1 = 512 + tid;
    const int sr0 = s0 >> 2, sr1 = s1 >> 2;
    const int r0 = sr0 ^ ((sr0 >> 2) & 1);
    const int r1 = sr1 ^ ((sr1 >> 2) & 1);
    const int q0 = (s0 & 3) ^ (r0 & 3);
    const int q1 = (s1 & 3) ^ (r1 & 3);
    const int offA0 = (bm + r0) * KSTR + q0 * 8;
    const int offA1 = (bm + r1) * KSTR + q1 * 8;
    const int offB0 = (bn + r0) * KSTR + q0 * 8;
    const int offB1 = (bn + r1) * KSTR + q1 * 8;

#define STAGE_A(buf, kt, kh) do {                                                          \
        gload16(A + offA0 + (kt) * 64 + (kh) * 32, AsB + ((buf) * 2 + (kh)) * 8192 + tid * 8); \
        gload16(A + offA1 + (kt) * 64 + (kh) * 32, AsB + ((buf) * 2 + (kh)) * 8192 + 4096 + tid * 8); \
    } while (0)
#define STAGE_B(buf, kt, kh) do {                                                          \
        gload16(Bt + offB0 + (kt) * 64 + (kh) * 32, BsB + ((buf) * 2 + (kh)) * 8192 + tid * 8); \
        gload16(Bt + offB1 + (kt) * 64 + (kh) * 32, BsB + ((buf) * 2 + (kh)) * 8192 + 4096 + tid * 8); \
    } while (0)

    const int c2 = (l16 >> 2) & 1;
    const int rdoff = ((l16 ^ c2) * 32) + ((quad ^ (l16 & 3)) * 8);

#define LDA(dst, buf, kh, mh) do {                                                         \
        _Pragma("unroll")                                                                  \
        for (int mi = 0; mi < 4; ++mi)                                                     \
            dst[mi] = *(const f16x8*)&AsB[((buf) * 2 + (kh)) * 8192 +                      \
                (wm * 128 + ((mh) * 4 + mi) * 16) * 32 + rdoff];                           \
    } while (0)
#define LDB(dst, buf, kh) do {                                                             \
        _Pragma("unroll")                                                                  \
        for (int ni = 0; ni < 4; ++ni)                                                     \
            dst[ni] = *(const f16x8*)&BsB[((buf) * 2 + (kh)) * 8192 +                      \
                (wn * 64 + ni * 16) * 32 + rdoff];                                         \
    } while (0)
#define MM(af, bf, mh) do {                                                                \
        __builtin_amdgcn_s_setprio(1);                                                     \
        _Pragma("unroll")                                                                  \
        for (int mi = 0; mi < 4; ++mi)                                                     \
            _Pragma("unroll")                                                              \
            for (int ni = 0; ni < 4; ++ni)                                                 \
                acc[(mh) * 4 + mi][ni] = __builtin_amdgcn_mfma_f32_16x16x32_f16(           \
                    af[mi], bf[ni], acc[(mh) * 4 + mi][ni], 0, 0, 0);                      \
        __builtin_amdgcn_s_setprio(0);                                                     \
    } while (0)

    // prologue: stage buf0 (tile0, both kh) + buf1.kh0 (tile1);
    // WAITV(4) completes buf0 (8 of 12 loads); preload r(p1) frags.
    STAGE_A(0, 0, 0); STAGE_B(0, 0, 0);
    STAGE_A(0, 0, 1); STAGE_B(0, 0, 1);
    STAGE_A(1, 1, 0); STAGE_B(1, 1, 0);
    WAITV(4);
    bar();
    LDA(afrA, 0, 0, 0); LDB(bfrA, 0, 0);

    #pragma unroll 1
    for (int i = 0; i < NTILES / 2 - 1; ++i) {
        const int t0 = 2 * i;
        // p1: MM buf0.kh0.mh0 | reads p2 (afrB) | stage buf1.kh1 <- t0+1 (A)
        STAGE_A(1, t0 + 1, 1);
        bar();
        LDA(afrB, 0, 0, 1);
        WAITL(4);
        MM(afrA, bfrA, 0);
        bar();
        // p2: MM buf0.kh0.mh1 | reads p3 (afrA + bfrB)
        STAGE_B(1, t0 + 1, 1);
        bar();
        LDA(afrA, 0, 1, 0); LDB(bfrB, 0, 1);
        WAITL(8);
        MM(afrB, bfrA, 1);
        bar();
        // p3: MM buf0.kh1.mh0 | reads p4 (afrB)
        STAGE_A(0, t0 + 2, 0);
        bar();
        LDA(afrB, 0, 1, 1);
        WAITL(4);
        MM(afrA, bfrB, 0);
        bar();
        // p4: MM buf0.kh1.mh1 | reads p5 (afrA + bfrA, buf1.kh0)
        STAGE_B(0, t0 + 2, 0); WAITV(4);
        bar();
        LDA(afrA, 1, 0, 0); LDB(bfrA, 1, 0);
        WAITL(8);
        MM(afrB, bfrB, 1);
        bar();
        // p5: MM buf1.kh0.mh0 | reads p6 (afrB)
        STAGE_A(0, t0 + 2, 1);
        bar();
        LDA(afrB, 1, 0, 1);
        WAITL(4);
        MM(afrA, bfrA, 0);
        bar();
        // p6: MM buf1.kh0.mh1 | reads p7 (afrA + bfrB, buf1.kh1)
        STAGE_B(0, t0 + 2, 1);
        bar();
        LDA(afrA, 1, 1, 0); LDB(bfrB, 1, 1);
        WAITL(8);
        MM(afrB, bfrA, 1);
        bar();
        // p7: MM buf1.kh1.mh0 | reads p8 (afrB)
        STAGE_A(1, t0 + 3, 0);
        bar();
        LDA(afrB, 1, 1, 1);
        WAITL(4);
        MM(afrA, bfrB, 0);
        bar();
        // p8: MM buf1.kh1.mh1 | reads next-p1 (afrA + bfrA, buf0.kh0 <- t0+2)
        STAGE_B(1, t0 + 3, 0); WAITV(4);
        bar();
        LDA(afrA, 0, 0, 0); LDB(bfrA, 0, 0);
        WAITL(8);
        MM(afrB, bfrB, 1);
        bar();
    }

    // epilogue: tiles NTILES-2 (buf0), NTILES-1 (buf1); stage buf1.kh1 only.
    // e1
    STAGE_A(1, NTILES - 1, 1);
    bar();
    LDA(afrB, 0, 0, 1);
    WAITL(4);
    MM(afrA, bfrA, 0);
    bar();
    // e2
    STAGE_B(1, NTILES - 1, 1);
    bar();
    LDA(afrA, 0, 1, 0); LDB(bfrB, 0, 1);
    WAITL(8);
    MM(afrB, bfrA, 1);
    bar();
    // e3
    bar();
    LDA(afrB, 0, 1, 1);
    WAITL(4);
    MM(afrA, bfrB, 0);
    bar();
    // e4: WAITV(4) completes buf1.kh0 (leaves e1/e2 stage loads)
    WAITV(4);
    bar();
    LDA(afrA, 1, 0, 0); LDB(bfrA, 1, 0);
    WAITL(8);
    MM(afrB, bfrB, 1);
    bar();
    // e5
    bar();
    LDA(afrB, 1, 0, 1);
    WAITL(4);
    MM(afrA, bfrA, 0);
    bar();
    // e6: WAITV(0) completes buf1.kh1
    WAITV(0);
    bar();
    LDA(afrA, 1, 1, 0); LDB(bfrB, 1, 1);
    WAITL(8);
    MM(afrB, bfrA, 1);
    bar();
    // e7
    bar();
    LDA(afrB, 1, 1, 1);
    WAITL(4);
    MM(afrA, bfrB, 0);
    bar();
    // e8
    WAITL(0);
    MM(afrB, bfrB, 1);

#undef STAGE_A
#undef STAGE_B
#undef LDA
#undef LDB
#undef MM

    #pragma unroll
    for (int mi = 0; mi < 8; ++mi)
        #pragma unroll
        for (int ni = 0; ni < 4; ++ni)
            #pragma unroll
            for (int r = 0; r < 4; ++r) {
                int row = bm + wm * 128 + mi * 16 + quad * 4 + r;
                int col = bn + wn * 64 + ni * 16 + l16;
                C[(size_t)row * 4096 + col] = (_Float16)acc[mi][ni][r];
            }
}

// ---------------------------------------------------------------------------
__global__ __launch_bounds__(512, 2) void gemm1_kernel(const _Float16* __restrict__ Fp,
                                                       const _Float16* __restrict__ Wn,
                                                       _Float16* __restrict__ S0) {
    __shared__ __align__(16) _Float16 As[2][2][8192];
    __shared__ __align__(16) _Float16 Bs[2][2][8192];
    const int z = blockIdx.z;
    gemm_core<1152, 18>(Fp + (size_t)z * 4718592, Wn + (size_t)z * 4718592,
                        S0 + (size_t)z * 16777216, &As[0][0][0], &Bs[0][0][0]);
}

// ---------------------------------------------------------------------------
__global__ __launch_bounds__(512, 2) void gemm2_kernel(const _Float16* __restrict__ Vt,
                                                       const _Float16* __restrict__ att0,
                                                       const _Float16* __restrict__ att1,
                                                       _Float16* __restrict__ OTh) {
    __shared__ __align__(16) _Float16 As[2][2][8192];
    __shared__ __align__(16) _Float16 Bs[2][2][8192];
    const int z = blockIdx.z;
    gemm_core<4096, 64>(Vt + (size_t)z * 8388608, z ? att1 : att0,
                        OTh + (size_t)z * 8388608, &As[0][0][0], &Bs[0][0][0]);
}

// ---------------------------------------------------------------------------
// Fused double 3-tap "fuse" + mask + softmax (R8 body, XCD swizzle, both
// batches in one dispatch).
__global__ __launch_bounds__(256) void fuse_softmax_kernel(const _Float16* __restrict__ S0,
                                                           const float* __restrict__ mm,
                                                           _Float16* __restrict__ att0,
                                                           _Float16* __restrict__ att1) {
    __shared__ float red[4];
    const int tid = threadIdx.x;
    const int lane = tid & 63;
    const int wave = tid >> 6;
    int g = blockIdx.x;
    int p_global = ((g & 7) << 10) | (g >> 3);
    const int bb = p_global >> 12;
    const int p = p_global & 4095;
    const _Float16* S = S0 + (size_t)bb * 16777216;
    _Float16* att = bb ? att1 : att0;
    const int pbase = ((p & 63) << 6) | (p >> 6);  // T(p)

    float acc[16];
    #pragma unroll
    for (int k = 0; k < 16; ++k) acc[k] = 0.f;

    #pragma unroll
    for (int t2 = -1; t2 <= 1; ++t2) {
        int b2 = pbase + t2;
        if ((unsigned)b2 >= 4096u) continue;
        int pp = ((b2 & 63) << 6) | (b2 >> 6);
        #pragma unroll
        for (int t1 = -1; t1 <= 1; ++t1) {
            int rr = pp + t1;
            if ((unsigned)rr >= 4096u) continue;
            const _Float16* row = S + (size_t)rr * 4096;
            #pragma unroll
            for (int k = 0; k < 16; ++k) {
                int l = k * 256 + tid;
                int i = (k * 256 + wave * 64) >> 6;
                int it2 = i + t2;
                if (it2 >= 0 && it2 < 64) {
                    int c = l + t2 * 64 + t1;
                    if ((unsigned)c < 4096u)
                        acc[k] += (float)row[c];
                } else if (it2 == 64) {
                    if (lane <= 62) {
                        int c = lane + 1 + t1;
                        if ((unsigned)c < 4096u) acc[k] += (float)row[c];
                    }
                } else {
                    if (lane >= 1) {
                        int c = 4031 + lane + t1;
                        if ((unsigned)c < 4096u) acc[k] += (float)row[c];
                    }
                }
            }
        }
    }

    float mv[16];
    float lmax = -1e30f;
    #pragma unroll
    for (int k = 0; k < 16; ++k) {
        int l = k * 256 + tid;
        mv[k] = mm[l];
        float lg = acc[k] * mv[k] * 10.0f;
        acc[k] = lg;
        lmax = fmaxf(lmax, lg);
    }
    #pragma unroll
    for (int off = 32; off > 0; off >>= 1) lmax = fmaxf(lmax, __shfl_xor(lmax, off));
    if (lane == 0) red[wave] = lmax;
    __syncthreads();
    lmax = fmaxf(fmaxf(red[0], red[1]), fmaxf(red[2], red[3]));
    __syncthreads();

    float lsum = 0.f;
    #pragma unroll
    for (int k = 0; k < 16; ++k) {
        float e = __expf(acc[k] - lmax);
        acc[k] = e;
        lsum += e;
    }
    #pragma unroll
    for (int off = 32; off > 0; off >>= 1) lsum += __shfl_xor(lsum, off);
    if (lane == 0) red[wave] = lsum;
    __syncthreads();
    float inv = 1.0f / (red[0] + red[1] + red[2] + red[3]);
    #pragma unroll
    for (int k = 0; k < 16; ++k) {
        int l = k * 256 + tid;
        att[(size_t)p * 4096 + l] = (_Float16)(acc[k] * inv * mv[k]);
    }
}

// ---------------------------------------------------------------------------
__global__ __launch_bounds__(256) void assemble_kernel(const _Float16* __restrict__ OTh,
                                                       float* __restrict__ out) {
    int idx = blockIdx.x * 256 + threadIdx.x;
    int bb = idx >> 21;
    int w = idx & 2097151;
    const _Float16* OTb = OTh + (size_t)bb * 8388608;
    int x = w & 127, y = (w >> 7) & 127, c = w >> 14;
    int r0 = (y + 1) & 1, s0 = (x + 1) & 1;
    float acc = 0.f;
    #pragma unroll
    for (int a = 0; a < 2; ++a) {
        int rh = r0 + 2 * a;
        int ph = (y + 1 - rh) >> 1;
        if ((unsigned)ph < 64u) {
            #pragma unroll
            for (int bq = 0; bq < 2; ++bq) {
                int rw = s0 + 2 * bq;
                int pw = (x + 1 - rw) >> 1;
                if ((unsigned)pw < 64u)
                    acc += (float)OTb[(size_t)(c * 16 + rh * 4 + rw) * 4096 + ph * 64 + pw];
            }
        }
    }
    out[idx] = 0.25f * acc;
}

// ---------------------------------------------------------------------------
extern "C" void kernel_launch(void* const* d_in, const int* in_sizes, int n_in,
                              void* d_out, int out_size, void* d_ws, size_t ws_size,
                              hipStream_t stream) {
    const float* f = (const float*)d_in[0];
    const float* b = (const float*)d_in[1];
    const float* mask = (const float*)d_in[2];
    float* out = (float*)d_out;
    char* ws = (char*)d_ws;

    // workspace — total 138,428,416 bytes (proven size)
    float* mm = (float*)ws;
    _Float16* Fp = (_Float16*)(ws + 16384);
    _Float16* Wn = (_Float16*)(ws + 16384 + 18874368);
    _Float16* att0 = (_Float16*)(ws + 16384);                 // overlays Fp/Wn (dead)
    _Float16* S0 = (_Float16*)(ws + 37765120);
    _Float16* Vt = (_Float16*)(ws + 37765120);                // overlays S0 b0 (dead)
    _Float16* OTh = (_Float16*)(ws + 37765120 + 33554432);    // overlays S0 b1 (dead)
    float* fds = (float*)(ws + 104873984);
    float* bds = (float*)(ws + 104873984 + 4194304);
    _Float16* att1 = (_Float16*)(ws + 104873984);             // overlays fds/bds (dead)

    downsample_kernel<<<dim3(4096, 2), 256, 0, stream>>>(f, b, fds, bds);
    build_mm_kernel<<<16, 256, 0, stream>>>(mask, mm);
    build_fpatch_kernel<<<8192, 256, 0, stream>>>(fds, Fp);
    build_wn_kernel<<<8192, 256, 0, stream>>>(bds, Wn);

    gemm1_kernel<<<dim3(16, 16, 2), 512, 0, stream>>>(Fp, Wn, S0);
    fuse_softmax_kernel<<<8192, 256, 0, stream>>>(S0, mm, att0, att1);

    build_vt_kernel<<<4096, 256, 0, stream>>>(b, Vt);
    gemm2_kernel<<<dim3(16, 8, 2), 512, 0, stream>>>(Vt, att0, att1, OTh);
    assemble_kernel<<<16384, 256, 0, stream>>>(OTh, out);
}

// Round 7
// 423.411 us; speedup vs baseline: 1.2425x; 1.0399x over previous
//
#include <hip/hip_runtime.h>
#include <cstdint>

typedef _Float16 f16x8 __attribute__((ext_vector_type(8)));
typedef float f32x4 __attribute__((ext_vector_type(4)));

typedef __attribute__((address_space(1))) void gvoid;
typedef __attribute__((address_space(3))) void lvoid;

__device__ __forceinline__ void gload16(const void* g, void* l) {
    __builtin_amdgcn_global_load_lds((gvoid*)g, (lvoid*)l, 16, 0, 0);
}

__device__ __forceinline__ void bar() {
    asm volatile("" ::: "memory");
    __builtin_amdgcn_s_barrier();
    asm volatile("" ::: "memory");
}
#define WAITV(N) asm volatile("s_waitcnt vmcnt(" #N ")" ::: "memory")

// ---------------------------------------------------------------------------
__global__ __launch_bounds__(256) void downsample_kernel(const float* __restrict__ f,
                                                         const float* __restrict__ b,
                                                         float* __restrict__ fds,
                                                         float* __restrict__ bds) {
    int idx = blockIdx.x * 256 + threadIdx.x;
    const float* src = blockIdx.y ? b : f;
    float* dst = blockIdx.y ? bds : fds;
    int bb = idx >> 19;
    int r = idx & 524287;
    int c = r >> 12, a = (r >> 6) & 63, v = r & 63;
    dst[idx] = src[(size_t)bb * 2097152 + (size_t)c * 16384 + (2 * a) * 128 + 2 * v];
}

// ---------------------------------------------------------------------------
__global__ __launch_bounds__(256) void build_mm_kernel(const float* __restrict__ mask,
                                                       float* __restrict__ mm) {
    int l = blockIdx.x * 256 + threadIdx.x;
    if (l >= 4096) return;
    int i = l >> 6, j = l & 63;
    float s = 0.f;
    #pragma unroll
    for (int dy = 0; dy < 3; ++dy)
        #pragma unroll
        for (int dx = 0; dx < 3; ++dx) {
            int a = i + dy - 1, b = j + dx - 1;
            if ((unsigned)a < 64u && (unsigned)b < 64u)
                s += mask[(2 * a) * 128 + 2 * b];
        }
    mm[l] = (s == 0.0f) ? 1.0f : 0.0f;
}

// ---------------------------------------------------------------------------
__global__ __launch_bounds__(256) void build_fpatch_kernel(const float* __restrict__ fds,
                                                           _Float16* __restrict__ Fp) {
    int bb = blockIdx.x >> 12;
    int p = blockIdx.x & 4095;
    const float* fb = fds + (size_t)bb * 524288;
    _Float16* Fpb = Fp + (size_t)bb * 4718592;
    int u = p >> 6, v = p & 63;
    for (int k = threadIdx.x; k < 1152; k += 256) {
        int c = k / 9;
        int s = k - 9 * c;
        int dy = s / 3, dx = s - 3 * dy;
        int a = u + dy - 1, bcol = v + dx - 1;
        float val = 0.f;
        if ((unsigned)a < 64u && (unsigned)bcol < 64u)
            val = fb[c * 4096 + a * 64 + bcol];
        Fpb[(size_t)p * 1152 + k] = (_Float16)val;
    }
}

// ---------------------------------------------------------------------------
__global__ __launch_bounds__(256) void build_wn_kernel(const float* __restrict__ bds,
                                                       _Float16* __restrict__ Wn) {
    __shared__ float wsh[1152];
    __shared__ float red[4];
    int bb = blockIdx.x >> 12;
    int l = blockIdx.x & 4095;
    const float* bp = bds + (size_t)bb * 524288;
    _Float16* Wnb = Wn + (size_t)bb * 4718592;
    int i = l >> 6, j = l & 63;
    float sq = 0.f;
    for (int k = threadIdx.x; k < 1152; k += 256) {
        int c = k / 9;
        int s = k - 9 * c;
        int dy = s / 3, dx = s - 3 * dy;
        int a = i + dy - 1, bcol = j + dx - 1;
        float val = 0.f;
        if ((unsigned)a < 64u && (unsigned)bcol < 64u)
            val = bp[c * 4096 + a * 64 + bcol];
        wsh[k] = val;
        sq += val * val;
    }
    #pragma unroll
    for (int off = 32; off > 0; off >>= 1) sq += __shfl_xor(sq, off);
    if ((threadIdx.x & 63) == 0) red[threadIdx.x >> 6] = sq;
    __syncthreads();
    float total = red[0] + red[1] + red[2] + red[3] + 0.1152f;
    float rinv = 1.0f / sqrtf(total);
    for (int k = threadIdx.x; k < 1152; k += 256)
        Wnb[(size_t)l * 1152 + k] = (_Float16)(wsh[k] * rinv);
}

// ---------------------------------------------------------------------------
__global__ __launch_bounds__(256) void build_vt_kernel(const float* __restrict__ b,
                                                       _Float16* __restrict__ Vt) {
    int bb = blockIdx.x >> 11;
    int n = blockIdx.x & 2047;
    const float* bp = b + (size_t)bb * 2097152;
    _Float16* Vtb = Vt + (size_t)bb * 8388608;
    int c = n >> 4, r = n & 15, rh = r >> 2, rw = r & 3;
    const float* bc = bp + (size_t)c * 16384;
    for (int l = threadIdx.x; l < 4096; l += 256) {
        int lh = l >> 6, lw = l & 63;
        int row = 2 * lh + rh - 1, col = 2 * lw + rw - 1;
        float val = 0.f;
        if ((unsigned)row < 128u && (unsigned)col < 128u)
            val = bc[row * 128 + col];
        Vtb[(size_t)n * 4096 + l] = (_Float16)val;
    }
}

// ---------------------------------------------------------------------------
// 256x256/BK=64 8-phase GEMM core (plain R1/R2 schedule — measured-equal to
// every pinned/rotated variant; the phase is LDS-pipe-bound, R2-R6 evidence).
// Phase p = { LD(frags p); STAGE; [WAITV(4) @ p4,p8]; bar; MFMA(p); bar }.
// Region/wait schedule (verified R1):
//   issue(i,p1/p2): buf1.Kh1 <- tile 2i+1   (read at i,p7/p8)
//   issue(i,p3/p4): buf0.Kh0 <- tile 2i+2   (read at i+1,p1/p2)
//   issue(i,p5/p6): buf0.Kh1 <- tile 2i+2   (read at i+1,p3/p4)
//   issue(i,p7/p8): buf1.Kh0 <- tile 2i+3   (read at i+1,p5/p6)
// Accumulation order per acc element unchanged -> numerics identical.
template <int KSTR, int NTILES>
__device__ __forceinline__ void gemm_core(const _Float16* __restrict__ A,
                                          const _Float16* __restrict__ Bt,
                                          _Float16* __restrict__ C,
                                          _Float16* __restrict__ AsB,
                                          _Float16* __restrict__ BsB) {
    const int tid = threadIdx.x;
    const int lane = tid & 63;
    const int wave = tid >> 6;
    const int quad = lane >> 4;
    const int l16 = lane & 15;
    const int wm = wave >> 2;
    const int wn = wave & 3;
    const int bm = blockIdx.y * 256;
    const int bn = blockIdx.x * 256;

    f32x4 acc[8][4] = {};

    const int s0 = tid, s1 = 512 + tid;
    const int sr0 = s0 >> 2, sr1 = s1 >> 2;
    const int r0 = sr0 ^ ((sr0 >> 2) & 1);
    const int r1 = sr1 ^ ((sr1 >> 2) & 1);
    const int q0 = (s0 & 3) ^ (r0 & 3);
    const int q1 = (s1 & 3) ^ (r1 & 3);
    const int offA0 = (bm + r0) * KSTR + q0 * 8;
    const int offA1 = (bm + r1) * KSTR + q1 * 8;
    const int offB0 = (bn + r0) * KSTR + q0 * 8;
    const int offB1 = (bn + r1) * KSTR + q1 * 8;

#define STAGE_A(buf, kt, kh) do {                                                          \
        gload16(A + offA0 + (kt) * 64 + (kh) * 32, AsB + ((buf) * 2 + (kh)) * 8192 + tid * 8); \
        gload16(A + offA1 + (kt) * 64 + (kh) * 32, AsB + ((buf) * 2 + (kh)) * 8192 + 4096 + tid * 8); \
    } while (0)
#define STAGE_B(buf, kt, kh) do {                                                          \
        gload16(Bt + offB0 + (kt) * 64 + (kh) * 32, BsB + ((buf) * 2 + (kh)) * 8192 + tid * 8); \
        gload16(Bt + offB1 + (kt) * 64 + (kh) * 32, BsB + ((buf) * 2 + (kh)) * 8192 + 4096 + tid * 8); \
    } while (0)

    const int c2 = (l16 >> 2) & 1;
    const int rdoff = ((l16 ^ c2) * 32) + ((quad ^ (l16 & 3)) * 8);

    f16x8 afr[4], bfr[4];
    auto LDA = [&](int buf, int kh, int mh) {
        #pragma unroll
        for (int mi = 0; mi < 4; ++mi)
            afr[mi] = *(const f16x8*)&AsB[((buf) * 2 + (kh)) * 8192 +
                                          (wm * 128 + ((mh) * 4 + mi) * 16) * 32 + rdoff];
    };
    auto LDB = [&](int buf, int kh) {
        #pragma unroll
        for (int ni = 0; ni < 4; ++ni)
            bfr[ni] = *(const f16x8*)&BsB[((buf) * 2 + (kh)) * 8192 +
                                          (wn * 64 + ni * 16) * 32 + rdoff];
    };
    auto MM = [&](int mh) {
        __builtin_amdgcn_s_setprio(1);
        #pragma unroll
        for (int mi = 0; mi < 4; ++mi)
            #pragma unroll
            for (int ni = 0; ni < 4; ++ni)
                acc[mh * 4 + mi][ni] = __builtin_amdgcn_mfma_f32_16x16x32_f16(
                    afr[mi], bfr[ni], acc[mh * 4 + mi][ni], 0, 0, 0);
        __builtin_amdgcn_s_setprio(0);
    };

    // prologue: 6 half-tile units; keep last 2 in flight
    STAGE_A(0, 0, 0); STAGE_B(0, 0, 0);
    STAGE_A(0, 0, 1); STAGE_B(0, 0, 1);
    STAGE_A(1, 1, 0); STAGE_B(1, 1, 0);
    WAITV(4);
    bar();

    #pragma unroll 1
    for (int i = 0; i < NTILES / 2 - 1; ++i) {
        const int t0 = 2 * i;
        LDA(0, 0, 0); LDB(0, 0); STAGE_A(1, t0 + 1, 1);
        bar(); MM(0); bar();
        LDA(0, 0, 1); STAGE_B(1, t0 + 1, 1);
        bar(); MM(1); bar();
        LDA(0, 1, 0); LDB(0, 1); STAGE_A(0, t0 + 2, 0);
        bar(); MM(0); bar();
        LDA(0, 1, 1); STAGE_B(0, t0 + 2, 0); WAITV(4);
        bar(); MM(1); bar();
        LDA(1, 0, 0); LDB(1, 0); STAGE_A(0, t0 + 2, 1);
        bar(); MM(0); bar();
        LDA(1, 0, 1); STAGE_B(0, t0 + 2, 1);
        bar(); MM(1); bar();
        LDA(1, 1, 0); LDB(1, 1); STAGE_A(1, t0 + 3, 0);
        bar(); MM(0); bar();
        LDA(1, 1, 1); STAGE_B(1, t0 + 3, 0); WAITV(4);
        bar(); MM(1); bar();
    }

    // epilogue: tiles NTILES-2 (buf0), NTILES-1 (buf1); stage buf1.kh1 only
    LDA(0, 0, 0); LDB(0, 0); STAGE_A(1, NTILES - 1, 1);
    bar(); MM(0); bar();
    LDA(0, 0, 1); STAGE_B(1, NTILES - 1, 1);
    bar(); MM(1); bar();
    LDA(0, 1, 0); LDB(0, 1);
    bar(); MM(0); bar();
    LDA(0, 1, 1);
    bar(); MM(1); WAITV(0); bar();
    LDA(1, 0, 0); LDB(1, 0); bar(); MM(0); bar();
    LDA(1, 0, 1);            bar(); MM(1); bar();
    LDA(1, 1, 0); LDB(1, 1); bar(); MM(0); bar();
    LDA(1, 1, 1);            bar(); MM(1);

#undef STAGE_A
#undef STAGE_B

    #pragma unroll
    for (int mi = 0; mi < 8; ++mi)
        #pragma unroll
        for (int ni = 0; ni < 4; ++ni)
            #pragma unroll
            for (int r = 0; r < 4; ++r) {
                int row = bm + wm * 128 + mi * 16 + quad * 4 + r;
                int col = bn + wn * 64 + ni * 16 + l16;
                C[(size_t)row * 4096 + col] = (_Float16)acc[mi][ni][r];
            }
}

// ---------------------------------------------------------------------------
__global__ __launch_bounds__(512, 2) void gemm1_kernel(const _Float16* __restrict__ Fp,
                                                       const _Float16* __restrict__ Wn,
                                                       _Float16* __restrict__ S0) {
    __shared__ __align__(16) _Float16 As[2][2][8192];
    __shared__ __align__(16) _Float16 Bs[2][2][8192];
    const int z = blockIdx.z;
    gemm_core<1152, 18>(Fp + (size_t)z * 4718592, Wn + (size_t)z * 4718592,
                        S0 + (size_t)z * 16777216, &As[0][0][0], &Bs[0][0][0]);
}

// ---------------------------------------------------------------------------
__global__ __launch_bounds__(512, 2) void gemm2_kernel(const _Float16* __restrict__ Vt,
                                                       const _Float16* __restrict__ att0,
                                                       const _Float16* __restrict__ att1,
                                                       _Float16* __restrict__ OTh) {
    __shared__ __align__(16) _Float16 As[2][2][8192];
    __shared__ __align__(16) _Float16 Bs[2][2][8192];
    const int z = blockIdx.z;
    gemm_core<4096, 64>(Vt + (size_t)z * 8388608, z ? att1 : att0,
                        OTh + (size_t)z * 8388608, &As[0][0][0], &Bs[0][0][0]);
}

// ---------------------------------------------------------------------------
// Fused double 3-tap "fuse" + mask + softmax — VECTORIZED rewrite.
// Each thread owns 16 CONSECUTIVE l (l0 = tid*16): i = l>>6 is thread-uniform,
// so the it2-wrap cases (it2==64 / ==-1) become per-thread branches, and the
// 9 (t2,t1) stencil taps read an 18-half register window per row via
// 2 aligned f16x8 loads + <=2 edge scalars (vs 144 scalar loads before).
// Contribution identity (derived from the verified R0 body; j = l&63):
//   case A (0<=it2<64): row[it2*64 + j + t1]   (OOB -> skip)
//   case B (it2==64):   row[j + 1 + t1]        gate j<=62
//   case C (it2==-1):   row[4031 + j + t1]     gate j>=1
// Unified: w[x] = row[ws+x], tap = w[e+1+t1];  A: ws=it2*64+j0-1 (w[0]/w[17]
// zero-if-OOB), B: ws=j0, C: ws=4030+j0.  Per-element add order (t2 outer,
// t1 inner) preserved -> accumulation bitwise-identical (skip == add 0.0f).
// mm loads, att stores now fully coalesced (16 consecutive per thread).
__global__ __launch_bounds__(256) void fuse_softmax_kernel(const _Float16* __restrict__ S0,
                                                           const float* __restrict__ mm,
                                                           _Float16* __restrict__ att0,
                                                           _Float16* __restrict__ att1) {
    __shared__ float red[4];
    const int tid = threadIdx.x;
    const int lane = tid & 63;
    const int wave = tid >> 6;
    int g = blockIdx.x;
    int p_global = ((g & 7) << 10) | (g >> 3);
    const int bb = p_global >> 12;
    const int p = p_global & 4095;
    const _Float16* S = S0 + (size_t)bb * 16777216;
    _Float16* att = bb ? att1 : att0;
    const int pbase = ((p & 63) << 6) | (p >> 6);  // T(p)

    const int i  = tid >> 2;          // l>>6, uniform across the thread's 16 l
    const int j0 = (tid & 3) << 4;    // start within the 64-block
    const int l0 = tid * 16;

    float acc[16];
    #pragma unroll
    for (int e = 0; e < 16; ++e) acc[e] = 0.f;

    #pragma unroll
    for (int t2 = -1; t2 <= 1; ++t2) {
        int b2 = pbase + t2;
        if ((unsigned)b2 >= 4096u) continue;
        int pp = ((b2 & 63) << 6) | (b2 >> 6);
        const int it2 = i + t2;
        #pragma unroll
        for (int t1 = -1; t1 <= 1; ++t1) {
            int rr = pp + t1;
            if ((unsigned)rr >= 4096u) continue;
            const _Float16* row = S + (size_t)rr * 4096;
            if ((unsigned)it2 < 64u) {
                // hot path: aligned 16-half core + 2 edge scalars
                const int ws = it2 * 64 + j0 - 1;
                float w[18];
                f16x8 v0 = *(const f16x8*)&row[ws + 1];
                f16x8 v1 = *(const f16x8*)&row[ws + 9];
                w[0]  = (ws >= 0) ? (float)row[ws] : 0.f;
                #pragma unroll
                for (int x = 0; x < 8; ++x) {
                    w[1 + x] = (float)v0[x];
                    w[9 + x] = (float)v1[x];
                }
                w[17] = (ws + 17 < 4096) ? (float)row[ws + 17] : 0.f;
                #pragma unroll
                for (int e = 0; e < 16; ++e) acc[e] += w[e + 1 + t1];
            } else if (it2 == 64) {
                #pragma unroll
                for (int e = 0; e < 16; ++e)
                    if (j0 + e <= 62) acc[e] += (float)row[j0 + e + 1 + t1];
            } else {  // it2 == -1
                #pragma unroll
                for (int e = 0; e < 16; ++e)
                    if (j0 + e >= 1) acc[e] += (float)row[4031 + j0 + e + t1];
            }
        }
    }

    float mv[16];
    float lmax = -1e30f;
    #pragma unroll
    for (int e = 0; e < 16; ++e) {
        mv[e] = mm[l0 + e];           // 16 consecutive f32 -> dwordx4 merged
        float lg = acc[e] * mv[e] * 10.0f;
        acc[e] = lg;
        lmax = fmaxf(lmax, lg);
    }
    #pragma unroll
    for (int off = 32; off > 0; off >>= 1) lmax = fmaxf(lmax, __shfl_xor(lmax, off));
    if (lane == 0) red[wave] = lmax;
    __syncthreads();
    lmax = fmaxf(fmaxf(red[0], red[1]), fmaxf(red[2], red[3]));
    __syncthreads();

    float lsum = 0.f;
    #pragma unroll
    for (int e = 0; e < 16; ++e) {
        float ex = __expf(acc[e] - lmax);
        acc[e] = ex;
        lsum += ex;
    }
    #pragma unroll
    for (int off = 32; off > 0; off >>= 1) lsum += __shfl_xor(lsum, off);
    if (lane == 0) red[wave] = lsum;
    __syncthreads();
    float inv = 1.0f / (red[0] + red[1] + red[2] + red[3]);

    _Float16 outv[16];
    #pragma unroll
    for (int e = 0; e < 16; ++e) outv[e] = (_Float16)(acc[e] * inv * mv[e]);
    _Float16* dst = att + (size_t)p * 4096 + l0;
    *(f16x8*)&dst[0] = *(const f16x8*)&outv[0];
    *(f16x8*)&dst[8] = *(const f16x8*)&outv[8];
}

// ---------------------------------------------------------------------------
__global__ __launch_bounds__(256) void assemble_kernel(const _Float16* __restrict__ OTh,
                                                       float* __restrict__ out) {
    int idx = blockIdx.x * 256 + threadIdx.x;
    int bb = idx >> 21;
    int w = idx & 2097151;
    const _Float16* OTb = OTh + (size_t)bb * 8388608;
    int x = w & 127, y = (w >> 7) & 127, c = w >> 14;
    int r0 = (y + 1) & 1, s0 = (x + 1) & 1;
    float acc = 0.f;
    #pragma unroll
    for (int a = 0; a < 2; ++a) {
        int rh = r0 + 2 * a;
        int ph = (y + 1 - rh) >> 1;
        if ((unsigned)ph < 64u) {
            #pragma unroll
            for (int bq = 0; bq < 2; ++bq) {
                int rw = s0 + 2 * bq;
                int pw = (x + 1 - rw) >> 1;
                if ((unsigned)pw < 64u)
                    acc += (float)OTb[(size_t)(c * 16 + rh * 4 + rw) * 4096 + ph * 64 + pw];
            }
        }
    }
    out[idx] = 0.25f * acc;
}

// ---------------------------------------------------------------------------
extern "C" void kernel_launch(void* const* d_in, const int* in_sizes, int n_in,
                              void* d_out, int out_size, void* d_ws, size_t ws_size,
                              hipStream_t stream) {
    const float* f = (const float*)d_in[0];
    const float* b = (const float*)d_in[1];
    const float* mask = (const float*)d_in[2];
    float* out = (float*)d_out;
    char* ws = (char*)d_ws;

    // workspace — total 138,428,416 bytes (proven size)
    float* mm = (float*)ws;
    _Float16* Fp = (_Float16*)(ws + 16384);
    _Float16* Wn = (_Float16*)(ws + 16384 + 18874368);
    _Float16* att0 = (_Float16*)(ws + 16384);                 // overlays Fp/Wn (dead)
    _Float16* S0 = (_Float16*)(ws + 37765120);
    _Float16* Vt = (_Float16*)(ws + 37765120);                // overlays S0 b0 (dead)
    _Float16* OTh = (_Float16*)(ws + 37765120 + 33554432);    // overlays S0 b1 (dead)
    float* fds = (float*)(ws + 104873984);
    float* bds = (float*)(ws + 104873984 + 4194304);
    _Float16* att1 = (_Float16*)(ws + 104873984);             // overlays fds/bds (dead)

    downsample_kernel<<<dim3(4096, 2), 256, 0, stream>>>(f, b, fds, bds);
    build_mm_kernel<<<16, 256, 0, stream>>>(mask, mm);
    build_fpatch_kernel<<<8192, 256, 0, stream>>>(fds, Fp);
    build_wn_kernel<<<8192, 256, 0, stream>>>(bds, Wn);

    gemm1_kernel<<<dim3(16, 16, 2), 512, 0, stream>>>(Fp, Wn, S0);
    fuse_softmax_kernel<<<8192, 256, 0, stream>>>(S0, mm, att0, att1);

    build_vt_kernel<<<4096, 256, 0, stream>>>(b, Vt);
    gemm2_kernel<<<dim3(16, 8, 2), 512, 0, stream>>>(Vt, att0, att1, OTh);
    assemble_kernel<<<16384, 256, 0, stream>>>(OTh, out);
}